// Round 9
// baseline (80.678 us; speedup 1.0000x reference)
//
#include <hip/hip_runtime.h>
#include <math.h>

#define DD     768
#define NPIX   50176          // 224*224
#define NPIX4  12544          // NPIX/4
#define NK     16             // K-chunks for partial matvecs
#define FILLB  2048           // fill blocks
#define FTOT   (1538u*NPIX4)  // 19,292,672 float4s
#define FITER  37             // ceil(FTOT / (FILLB*256))

typedef float f4 __attribute__((ext_vector_type(4)));

// ---- workspace layout (float offsets) ----
#define WS_PART 0                       // 4 mats * NK * 768 partials
#define WS_TBL  (4*NK*DD)               // 1538-entry channel-value table:
                                        // [0..767]=alpha*pos, [768]=sb,
                                        // [769..1536]=dec_vec, [1537]=ml

// ---- output layout (float offsets, tuple order concatenated) ----
// maps region O_SPM..O_ML+NPIX is one contiguous 1538*NPIX block
#define O_PROMPT 0
#define O_SP     (O_PROMPT + DD)
#define O_SPM    (O_SP + DD)
#define O_SB     (O_SPM + (size_t)DD*NPIX)
#define O_DEC    (O_SB + NPIX)
#define O_ML     (O_DEC + (size_t)DD*NPIX)
#define O_ALPHA  (O_ML + NPIX)
#define O_NL     (O_ALPHA + 1)

__device__ __forceinline__ float gelu_exact(float x) {
    return 0.5f * x * (1.0f + erff(x * 0.70710678118654752f));
}
__device__ __forceinline__ float sigmoidf(float x) {
    return 1.0f / (1.0f + expf(-x));
}

// K1: partial matvecs (round-3 proven config). grid=(NK,3,4), block=256.
__global__ __launch_bounds__(256) void k_matvec_part(
    const float* __restrict__ pos, const float* __restrict__ neg,
    const float* __restrict__ bnd,
    const float* __restrict__ alpha_w1, const float* __restrict__ prompt_w,
    const float* __restrict__ dec_w,   const float* __restrict__ neg_w1,
    float* __restrict__ ws)
{
    const int kchunk = blockIdx.x, jchunk = blockIdx.y, m = blockIdx.z;
    const int tid = threadIdx.x;
    const int j = jchunk * 256 + tid;

    const float* W = (m == 0) ? alpha_w1 : (m == 1) ? prompt_w
                   : (m == 2) ? dec_w    : neg_w1;

    __shared__ float xs[144];
    if (m == 3) {
        const int k0 = kchunk * 48;
        if (tid < 48) xs[tid] = neg[k0 + tid];
    } else {
        const int k0 = kchunk * 144;
        if (tid < 144) {
            int k = k0 + tid;
            float v;
            if (k < DD)          v = pos[k];
            else if (k < 2 * DD) v = neg[k - DD];
            else                 v = bnd[k - 2 * DD];
            xs[tid] = v;
        }
    }
    __syncthreads();

    float acc = 0.0f;
    if (m == 3) {
        const float* Wp = W + (size_t)(kchunk * 48) * DD + j;
        #pragma unroll 24
        for (int kk = 0; kk < 48; ++kk)
            acc += xs[kk] * Wp[(size_t)kk * DD];
    } else {
        const float* Wp = W + (size_t)(kchunk * 144) * DD + j;
        #pragma unroll 24
        for (int kk = 0; kk < 144; ++kk)
            acc += xs[kk] * Wp[(size_t)kk * DD];
    }

    ws[WS_PART + (size_t)(m * NK + kchunk) * DD + j] = acc;
}

// K2: one block of 768 threads (12 waves) — all scalar/vector glue.
__global__ __launch_bounds__(768) void k_small(
    const float* __restrict__ query, const float* __restrict__ pos,
    const float* __restrict__ neg,   const float* __restrict__ bnd,
    const float* __restrict__ alpha_b1, const float* __restrict__ alpha_w2,
    const float* __restrict__ alpha_b2,
    const float* __restrict__ neg_b1,   const float* __restrict__ neg_w2,
    const float* __restrict__ neg_b2,
    const float* __restrict__ prompt_b, const float* __restrict__ dec_b,
    const float* __restrict__ logit_w,  const float* __restrict__ logit_b,
    float* __restrict__ ws, float* __restrict__ out)
{
    const int j = threadIdx.x;  // 0..767

    float a_h = 0.f, pr = 0.f, dc = 0.f, ng = 0.f;
    #pragma unroll
    for (int c = 0; c < NK; ++c) {
        a_h += ws[WS_PART + (0 * NK + c) * DD + j];
        pr  += ws[WS_PART + (1 * NK + c) * DD + j];
        dc  += ws[WS_PART + (2 * NK + c) * DD + j];
        ng  += ws[WS_PART + (3 * NK + c) * DD + j];
    }

    pr += prompt_b[j];
    const float dec_v = dc + dec_b[j];
    out[O_PROMPT + j]       = pr;     // prompt_tokens
    ws[WS_TBL + 769 + j]    = dec_v;  // decoder map channel value

    const float ga   = gelu_exact(a_h + alpha_b1[j]);
    const float gn   = gelu_exact(ng  + neg_b1[j]);
    const float negj = neg[j];
    const float lw   = logit_w[j];
    const float dbd  = bnd[j] - negj;

    float r[5];
    r[0] = ga * alpha_w2[j];
    r[1] = gn * neg_w2[j];
    r[2] = dec_v * lw;
    r[3] = negj * lw;
    r[4] = dbd * dbd;

    #pragma unroll
    for (int s = 32; s > 0; s >>= 1) {
        #pragma unroll
        for (int q = 0; q < 5; ++q) r[q] += __shfl_xor(r[q], s, 64);
    }

    __shared__ float red[5][12];
    const int wid = j >> 6, lane = j & 63;
    if (lane == 0) {
        #pragma unroll
        for (int q = 0; q < 5; ++q) red[q][wid] = r[q];
    }
    __syncthreads();

    __shared__ float sh_alpha;
    if (j == 0) {
        float s[5];
        #pragma unroll
        for (int q = 0; q < 5; ++q) {
            float t = 0.f;
            #pragma unroll
            for (int w = 0; w < 12; ++w) t += red[q][w];
            s[q] = t;
        }
        const float alpha = sigmoidf(s[0] + alpha_b2[0]);
        const float nl    = sigmoidf(s[1] + neg_b2[0]);
        const float ld    = s[2] + logit_b[0];
        const float ln    = s[3] + logit_b[0];
        out[O_ALPHA]       = alpha;
        out[O_NL]          = nl;
        ws[WS_TBL + 768]   = sqrtf(s[4]);      // sb
        ws[WS_TBL + 1537]  = ld - nl * ln;     // ml
        sh_alpha = alpha;
    }
    __syncthreads();

    const float alpha = sh_alpha;
    const float ap    = alpha * pos[j];
    out[O_SP + j]  = ap + (1.0f - alpha) * query[j];  // semantic_prototype
    ws[WS_TBL + j] = ap;                              // spm channel value
}

// K3: flat fill, load-phase/store-phase split, REGULAR stores.
// grid = 2048 blocks, block = 256. Each thread: up to 37 f4 stores.
__global__ __launch_bounds__(256) void k_fill(
    const float* __restrict__ ws, float* __restrict__ out)
{
    const float* tbl = ws + WS_TBL;
    f4* p = (f4*)(out + O_SPM);
    const unsigned base   = blockIdx.x * 256u + threadIdx.x;
    const unsigned stride = FILLB * 256u;

    // phase 1: issue all channel-value loads (independent, pipelined)
    float v[FITER];
    #pragma unroll
    for (int n = 0; n < FITER; ++n) {
        const unsigned i = base + (unsigned)n * stride;
        if (i < FTOT) v[n] = tbl[i / NPIX4];
    }
    // phase 2: pure store stream
    #pragma unroll
    for (int n = 0; n < FITER; ++n) {
        const unsigned i = base + (unsigned)n * stride;
        if (i < FTOT) {
            f4 v4 = {v[n], v[n], v[n], v[n]};
            p[i] = v4;
        }
    }
}

extern "C" void kernel_launch(void* const* d_in, const int* in_sizes, int n_in,
                              void* d_out, int out_size, void* d_ws, size_t ws_size,
                              hipStream_t stream) {
    const float* query    = (const float*)d_in[0];
    const float* pos      = (const float*)d_in[1];
    const float* neg      = (const float*)d_in[2];
    const float* bnd      = (const float*)d_in[3];
    // d_in[4] = spatial_map: values never used (shape-only in reference)
    const float* alpha_w1 = (const float*)d_in[5];
    const float* alpha_b1 = (const float*)d_in[6];
    const float* alpha_w2 = (const float*)d_in[7];
    const float* alpha_b2 = (const float*)d_in[8];
    const float* neg_w1   = (const float*)d_in[9];
    const float* neg_b1   = (const float*)d_in[10];
    const float* neg_w2   = (const float*)d_in[11];
    const float* neg_b2   = (const float*)d_in[12];
    const float* prompt_w = (const float*)d_in[13];
    const float* prompt_b = (const float*)d_in[14];
    const float* dec_w    = (const float*)d_in[15];
    const float* dec_b    = (const float*)d_in[16];
    const float* logit_w  = (const float*)d_in[17];
    const float* logit_b  = (const float*)d_in[18];

    float* out = (float*)d_out;
    float* ws  = (float*)d_ws;

    // K1: partial matvecs (round-3 proven config)
    k_matvec_part<<<dim3(NK, 3, 4), 256, 0, stream>>>(
        pos, neg, bnd, alpha_w1, prompt_w, dec_w, neg_w1, ws);

    // K2: reductions + scalar chain + small outputs + channel-value table
    k_small<<<1, DD, 0, stream>>>(
        query, pos, neg, bnd,
        alpha_b1, alpha_w2, alpha_b2,
        neg_b1, neg_w2, neg_b2,
        prompt_b, dec_b, logit_w, logit_b,
        ws, out);

    // K3: big broadcast fill (regular stores, load/store phase split)
    k_fill<<<FILLB, 256, 0, stream>>>(ws, out);
}

// Round 10
// 68.418 us; speedup vs baseline: 1.1792x; 1.1792x over previous
//
#include <hip/hip_runtime.h>
#include <math.h>

#define DD     768
#define NPIX   50176          // 224*224
#define NPIX4  12544          // NPIX/4
#define NK     16             // K-chunks per matrix

typedef float f4 __attribute__((ext_vector_type(4)));

// ---- workspace layout (float offsets) ----
#define WS_PART 0                       // 4 mats * NK * 768 partials
#define WS_TBL  (4*NK*DD)               // 1538-entry channel-value table:
                                        // [0..767]=alpha*pos, [768]=sb,
                                        // [769..1536]=dec_vec, [1537]=ml

// ---- output layout (float offsets, tuple order concatenated) ----
// maps region O_SPM..O_ML+NPIX is one contiguous 1538*NPIX block
#define O_PROMPT 0
#define O_SP     (O_PROMPT + DD)
#define O_SPM    (O_SP + DD)
#define O_SB     (O_SPM + (size_t)DD*NPIX)
#define O_DEC    (O_SB + NPIX)
#define O_ML     (O_DEC + (size_t)DD*NPIX)
#define O_ALPHA  (O_ML + NPIX)
#define O_NL     (O_ALPHA + 1)

__device__ __forceinline__ float gelu_exact(float x) {
    return 0.5f * x * (1.0f + erff(x * 0.70710678118654752f));
}
__device__ __forceinline__ float sigmoidf(float x) {
    return 1.0f / (1.0f + expf(-x));
}

// K1: partial matvecs. grid=(NK, 3, 4), block=256.  [proven round-3 config]
// m: 0=alpha_h (fused@alpha_w1), 1=prompt (fused@prompt_w),
//    2=dec (fused@dec_w),        3=neg_h (neg@neg_w1)
__global__ __launch_bounds__(256) void k_matvec_part(
    const float* __restrict__ pos, const float* __restrict__ neg,
    const float* __restrict__ bnd,
    const float* __restrict__ alpha_w1, const float* __restrict__ prompt_w,
    const float* __restrict__ dec_w,   const float* __restrict__ neg_w1,
    float* __restrict__ ws)
{
    const int kchunk = blockIdx.x, jchunk = blockIdx.y, m = blockIdx.z;
    const int tid = threadIdx.x;
    const int j = jchunk * 256 + tid;

    const float* W = (m == 0) ? alpha_w1 : (m == 1) ? prompt_w
                   : (m == 2) ? dec_w    : neg_w1;

    __shared__ float xs[144];
    if (m == 3) {
        const int k0 = kchunk * 48;
        if (tid < 48) xs[tid] = neg[k0 + tid];
    } else {
        const int k0 = kchunk * 144;
        if (tid < 144) {
            int k = k0 + tid;
            float v;
            if (k < DD)          v = pos[k];
            else if (k < 2 * DD) v = neg[k - DD];
            else                 v = bnd[k - 2 * DD];
            xs[tid] = v;
        }
    }
    __syncthreads();

    float acc = 0.0f;
    if (m == 3) {
        const float* Wp = W + (size_t)(kchunk * 48) * DD + j;
        #pragma unroll 24
        for (int kk = 0; kk < 48; ++kk)
            acc += xs[kk] * Wp[(size_t)kk * DD];
    } else {
        const float* Wp = W + (size_t)(kchunk * 144) * DD + j;
        #pragma unroll 24
        for (int kk = 0; kk < 144; ++kk)
            acc += xs[kk] * Wp[(size_t)kk * DD];
    }

    ws[WS_PART + (size_t)(m * NK + kchunk) * DD + j] = acc;
}

// K2: one block of 768 threads (12 waves) — all scalar/vector glue.
__global__ __launch_bounds__(768) void k_small(
    const float* __restrict__ query, const float* __restrict__ pos,
    const float* __restrict__ neg,   const float* __restrict__ bnd,
    const float* __restrict__ alpha_b1, const float* __restrict__ alpha_w2,
    const float* __restrict__ alpha_b2,
    const float* __restrict__ neg_b1,   const float* __restrict__ neg_w2,
    const float* __restrict__ neg_b2,
    const float* __restrict__ prompt_b, const float* __restrict__ dec_b,
    const float* __restrict__ logit_w,  const float* __restrict__ logit_b,
    float* __restrict__ ws, float* __restrict__ out)
{
    const int j = threadIdx.x;  // 0..767

    // reduce K-chunk partials (coalesced, L2-hot)
    float a_h = 0.f, pr = 0.f, dc = 0.f, ng = 0.f;
    #pragma unroll
    for (int c = 0; c < NK; ++c) {
        a_h += ws[WS_PART + (0 * NK + c) * DD + j];
        pr  += ws[WS_PART + (1 * NK + c) * DD + j];
        dc  += ws[WS_PART + (2 * NK + c) * DD + j];
        ng  += ws[WS_PART + (3 * NK + c) * DD + j];
    }

    pr += prompt_b[j];
    const float dec_v = dc + dec_b[j];
    out[O_PROMPT + j]       = pr;     // prompt_tokens
    ws[WS_TBL + 769 + j]    = dec_v;  // decoder map channel value

    const float ga   = gelu_exact(a_h + alpha_b1[j]);
    const float gn   = gelu_exact(ng  + neg_b1[j]);
    const float negj = neg[j];
    const float lw   = logit_w[j];
    const float dbd  = bnd[j] - negj;

    float r[5];
    r[0] = ga * alpha_w2[j];
    r[1] = gn * neg_w2[j];
    r[2] = dec_v * lw;
    r[3] = negj * lw;
    r[4] = dbd * dbd;

    // per-wave butterfly reduction (64 lanes)
    #pragma unroll
    for (int s = 32; s > 0; s >>= 1) {
        #pragma unroll
        for (int q = 0; q < 5; ++q) r[q] += __shfl_xor(r[q], s, 64);
    }

    __shared__ float red[5][12];
    const int wid = j >> 6, lane = j & 63;
    if (lane == 0) {
        #pragma unroll
        for (int q = 0; q < 5; ++q) red[q][wid] = r[q];
    }
    __syncthreads();

    __shared__ float sh_alpha;
    if (j == 0) {
        float s[5];
        #pragma unroll
        for (int q = 0; q < 5; ++q) {
            float t = 0.f;
            #pragma unroll
            for (int w = 0; w < 12; ++w) t += red[q][w];
            s[q] = t;
        }
        const float alpha = sigmoidf(s[0] + alpha_b2[0]);
        const float nl    = sigmoidf(s[1] + neg_b2[0]);
        const float ld    = s[2] + logit_b[0];
        const float ln    = s[3] + logit_b[0];
        out[O_ALPHA]       = alpha;
        out[O_NL]          = nl;
        ws[WS_TBL + 768]   = sqrtf(s[4]);      // sb
        ws[WS_TBL + 1537]  = ld - nl * ln;     // ml
        sh_alpha = alpha;
    }
    __syncthreads();

    const float alpha = sh_alpha;
    const float ap    = alpha * pos[j];
    out[O_SP + j]  = ap + (1.0f - alpha) * query[j];  // semantic_prototype
    ws[WS_TBL + j] = ap;                              // spm channel value
}

// K3: flat broadcast fill of the 1538*NPIX contiguous map region.
// grid = 2048 blocks (8/CU, balanced), block = 256. Nontemporal stores:
// measured +12 µs if replaced by regular stores (round-9 A/B).
__global__ __launch_bounds__(256) void k_fill(
    const float* __restrict__ ws, float* __restrict__ out)
{
    const float* tbl = ws + WS_TBL;
    f4* p = (f4*)(out + O_SPM);
    const unsigned total  = 1538u * NPIX4;        // 19,292,672 float4s
    const unsigned stride = gridDim.x * 256u;
    for (unsigned i = blockIdx.x * 256u + threadIdx.x; i < total; i += stride) {
        const unsigned c = i / NPIX4;             // magic-mul divide
        const float v = tbl[c];                   // wave-uniform -> broadcast
        f4 v4 = {v, v, v, v};
        __builtin_nontemporal_store(v4, p + i);
    }
}

extern "C" void kernel_launch(void* const* d_in, const int* in_sizes, int n_in,
                              void* d_out, int out_size, void* d_ws, size_t ws_size,
                              hipStream_t stream) {
    const float* query    = (const float*)d_in[0];
    const float* pos      = (const float*)d_in[1];
    const float* neg      = (const float*)d_in[2];
    const float* bnd      = (const float*)d_in[3];
    // d_in[4] = spatial_map: values never used (shape-only in reference)
    const float* alpha_w1 = (const float*)d_in[5];
    const float* alpha_b1 = (const float*)d_in[6];
    const float* alpha_w2 = (const float*)d_in[7];
    const float* alpha_b2 = (const float*)d_in[8];
    const float* neg_w1   = (const float*)d_in[9];
    const float* neg_b1   = (const float*)d_in[10];
    const float* neg_w2   = (const float*)d_in[11];
    const float* neg_b2   = (const float*)d_in[12];
    const float* prompt_w = (const float*)d_in[13];
    const float* prompt_b = (const float*)d_in[14];
    const float* dec_w    = (const float*)d_in[15];
    const float* dec_b    = (const float*)d_in[16];
    const float* logit_w  = (const float*)d_in[17];
    const float* logit_b  = (const float*)d_in[18];

    float* out = (float*)d_out;
    float* ws  = (float*)d_ws;

    // K1: partial matvecs
    k_matvec_part<<<dim3(NK, 3, 4), 256, 0, stream>>>(
        pos, neg, bnd, alpha_w1, prompt_w, dec_w, neg_w1, ws);

    // K2: reductions + scalar chain + small outputs + channel-value table
    k_small<<<1, DD, 0, stream>>>(
        query, pos, neg, bnd,
        alpha_b1, alpha_w2, alpha_b2,
        neg_b1, neg_w2, neg_b2,
        prompt_b, dec_b, logit_w, logit_b,
        ws, out);

    // K3: big broadcast fill (nontemporal, flat, balanced)
    k_fill<<<2048, 256, 0, stream>>>(ws, out);
}